// Round 1
// baseline (986.112 us; speedup 1.0000x reference)
//
#include <hip/hip_runtime.h>
#include <math.h>

// Problem constants
#define NPART   16384      // B*S
#define LAT     20
#define DH      80
#define NSTEP   40
#define TLEN    41
#define DIMA    22
// workspace float offsets
#define WT_IN_OFF   0        // [24][80]  = 1920
#define WT_H_OFF    1920     // [4][80][80] = 25600
#define WT_OUT_OFF  27520    // [80][20] = 1600
#define TRAJ_OFF    29120    // [41][16384] logqp trajectory
#define OUT0_ELEMS  13434880 // 41*16384*20

__device__ __forceinline__ float fast_tanh(float x) {
    float e = __expf(2.0f * x);
    return 1.0f - 2.0f * __builtin_amdgcn_rcpf(e + 1.0f);
}

// Pre-pass: transpose d-MLP weights to [k][j] so the main kernel's weight
// reads are wave-uniform consecutive dwords -> scalar s_load_dwordx8 streams.
__global__ void transpose_w(const float* __restrict__ dw_in,
                            const float* __restrict__ dw_h,
                            const float* __restrict__ dw_out,
                            float* __restrict__ WT) {
    int e = blockIdx.x * 256 + threadIdx.x;
    if (e < 1920) {
        int k = e / 80, j = e % 80;
        WT[WT_IN_OFF + e] = dw_in[j * 24 + k];
    } else if (e < 27520) {
        int r = e - 1920;
        int l = r / 6400, r2 = r % 6400;
        int k = r2 / 80, j = r2 % 80;
        WT[e] = dw_h[l * 6400 + j * 80 + k];
    } else if (e < 29120) {
        int r = e - 27520;
        int k = r / 20, j = r % 20;
        WT[e] = dw_out[j * 80 + k];
    }
}

__global__ __launch_bounds__(512) void sde_main(
    const float* __restrict__ z,      const float* __restrict__ t_arr,
    const float* __restrict__ Tx,     const float* __restrict__ noise,
    const float* __restrict__ tw_in,  const float* __restrict__ tb_in,
    const float* __restrict__ tw_h,   const float* __restrict__ tb_h,
    const float* __restrict__ tw_out, const float* __restrict__ tb_out,
    const float* __restrict__ db_in,  const float* __restrict__ db_h,
    const float* __restrict__ db_out,
    const float* __restrict__ WS,
    float* __restrict__ out0, float* __restrict__ traj)
{
    __shared__ float X[LAT][64];    // current y per particle
    __shared__ float Ha[DH][64];
    __shared__ float Hb[DH][64];
    __shared__ float Uall[NSTEP][4];
    __shared__ float Part[4][64];

    const int tid = threadIdx.x;
    const int p   = tid & 63;                                   // particle-in-block
    const int w   = __builtin_amdgcn_readfirstlane(tid >> 6);   // wave id (uniform)
    const int n   = blockIdx.x * 64 + p;                        // global particle
    const float Txb = Tx[blockIdx.x];   // all particles in block share b = n/64
    const float dtv = t_arr[1] - t_arr[0];
    const float sdt = sqrtf(dtv);
    const float* WT_in  = WS + WT_IN_OFF;
    const float* WT_h   = WS + WT_H_OFF;
    const float* WT_out = WS + WT_OUT_OFF;

    // ---- t-MLP: u(t_i) for i=0..39 (tiny; lanes 0..39 of wave 0) ----
    if (tid < NSTEP) {
        float ti = t_arr[tid];
        float h[20], h2[20];
        #pragma unroll
        for (int j = 0; j < 20; j++) {
            float v = tw_in[j] * ti + tb_in[j];
            h[j] = v > 0.f ? v : 0.f;
        }
        #pragma unroll
        for (int l = 0; l < 4; l++) {
            #pragma unroll
            for (int j = 0; j < 20; j++) {
                float a = tb_h[l * 20 + j];
                #pragma unroll
                for (int k = 0; k < 20; k++) a += tw_h[(l * 20 + j) * 20 + k] * h[k];
                h2[j] = a > 0.f ? a : 0.f;
            }
            #pragma unroll
            for (int j = 0; j < 20; j++) h[j] = h2[j];
        }
        #pragma unroll
        for (int c = 0; c < 4; c++) {
            float a = tb_out[c];
            #pragma unroll
            for (int k = 0; k < 20; k++) a += tw_out[c * 20 + k] * h[k];
            Uall[tid][c] = a;
        }
    }

    // ---- init y from z_SDE; emit t=0 snapshot (= z itself) ----
    if (w < 4) {
        #pragma unroll
        for (int j = 0; j < 5; j++) {
            int d = w * 5 + j;
            float v = z[(size_t)n * LAT + d];
            X[d][p] = v;
            out0[(size_t)n * LAT + d] = v;
        }
        if (w == 0) traj[n] = 0.f;
    }
    float lq = 0.f;  // logqp accumulator (wave 0 lanes)
    __syncthreads();

    const int r0 = w * 10;   // this wave's 10-row chunk of the 80-wide layers

    for (int i = 0; i < NSTEP; i++) {
        float ut[4];
        #pragma unroll
        for (int c = 0; c < 4; c++) ut[c] = Uall[i][c] * Txb;

        // ---- input layer: h1 = relu(W_in x + b), rows r0..r0+9 ----
        float acc[10];
        #pragma unroll
        for (int j = 0; j < 10; j++) acc[j] = db_in[r0 + j];
        #pragma unroll 4
        for (int k = 0; k < LAT; k++) {
            float xk = X[k][p];
            #pragma unroll
            for (int j = 0; j < 10; j++) acc[j] += WT_in[k * 80 + r0 + j] * xk;
        }
        #pragma unroll
        for (int c = 0; c < 4; c++) {
            float xk = ut[c];
            #pragma unroll
            for (int j = 0; j < 10; j++) acc[j] += WT_in[(LAT + c) * 80 + r0 + j] * xk;
        }
        #pragma unroll
        for (int j = 0; j < 10; j++) Ha[r0 + j][p] = acc[j] > 0.f ? acc[j] : 0.f;
        __syncthreads();

        // ---- 4 hidden tanh layers, ping-pong Ha<->Hb (final lands in Ha) ----
        #pragma unroll
        for (int l = 0; l < 4; l++) {
            const float* Hin = (l & 1) ? &Hb[0][0] : &Ha[0][0];
            float*       Hout = (l & 1) ? &Ha[0][0] : &Hb[0][0];
            const float* Wl = WT_h + l * 6400;
            #pragma unroll
            for (int j = 0; j < 10; j++) acc[j] = db_h[l * 80 + r0 + j];
            #pragma unroll 8
            for (int k = 0; k < DH; k++) {
                float hk = Hin[k * 64 + p];
                #pragma unroll
                for (int j = 0; j < 10; j++) acc[j] += Wl[k * 80 + r0 + j] * hk;
            }
            #pragma unroll
            for (int j = 0; j < 10; j++) Hout[(r0 + j) * 64 + p] = fast_tanh(acc[j]);
            __syncthreads();
        }

        // ---- output layer + SDE update: waves 0..3 each own 5 of 20 dims ----
        if (w < 4) {
            const int q0 = w * 5;
            float o[5];
            #pragma unroll
            for (int j = 0; j < 5; j++) o[j] = db_out[q0 + j];
            #pragma unroll 8
            for (int k = 0; k < DH; k++) {
                float hk = Ha[k][p];
                #pragma unroll
                for (int j = 0; j < 5; j++) o[j] += WT_out[k * 20 + q0 + j] * hk;
            }
            float part = 0.f;
            #pragma unroll
            for (int j = 0; j < 5; j++) {
                int d = q0 + j;
                float y  = X[d][p];
                float f  = o[j] + y;              // f = mlp - (-y)
                float uu = 2.f * o[j] + 4.f * y;  // (f - h)/SIGMA
                part += uu * uu;
                float dW = noise[((size_t)i * NPART + n) * DIMA + d];
                float yn = y + f * dtv + (0.5f * sdt) * dW;   // g = SIGMA = 0.5
                X[d][p] = yn;
                out0[((size_t)(i + 1) * NPART + n) * LAT + d] = yn;
            }
            Part[w][p] = part;
        }
        __syncthreads();
        if (w == 0) {
            float s = Part[0][p] + Part[1][p] + Part[2][p] + Part[3][p];
            lq += 0.5f * s * dtv;
            traj[(size_t)(i + 1) * NPART + n] = lq;
        }
    }
}

// logqp output: out1[i] = logqp trajectory at flat index 41*i + 40
// (the reference's reshape reinterprets (T, N) memory as (B, S, T')).
__global__ void gather_logqp(const float* __restrict__ traj, float* __restrict__ out1) {
    int i = blockIdx.x * 256 + threadIdx.x;
    if (i < NPART) out1[i] = traj[(size_t)41 * i + 40];
}

extern "C" void kernel_launch(void* const* d_in, const int* in_sizes, int n_in,
                              void* d_out, int out_size, void* d_ws, size_t ws_size,
                              hipStream_t stream) {
    const float* z      = (const float*)d_in[0];
    const float* t_arr  = (const float*)d_in[1];
    const float* Tx     = (const float*)d_in[2];
    const float* noise  = (const float*)d_in[3];
    const float* tw_in  = (const float*)d_in[4];
    const float* tb_in  = (const float*)d_in[5];
    const float* tw_h   = (const float*)d_in[6];
    const float* tb_h   = (const float*)d_in[7];
    const float* tw_out = (const float*)d_in[8];
    const float* tb_out = (const float*)d_in[9];
    const float* dw_in  = (const float*)d_in[10];
    const float* db_in  = (const float*)d_in[11];
    const float* dw_h   = (const float*)d_in[12];
    const float* db_h   = (const float*)d_in[13];
    const float* dw_out = (const float*)d_in[14];
    const float* db_out = (const float*)d_in[15];

    float* ws   = (float*)d_ws;
    float* traj = ws + TRAJ_OFF;
    float* out0 = (float*)d_out;
    float* out1 = out0 + OUT0_ELEMS;

    hipLaunchKernelGGL(transpose_w, dim3(114), dim3(256), 0, stream,
                       dw_in, dw_h, dw_out, ws);
    hipLaunchKernelGGL(sde_main, dim3(256), dim3(512), 0, stream,
                       z, t_arr, Tx, noise, tw_in, tb_in, tw_h, tb_h,
                       tw_out, tb_out, db_in, db_h, db_out, ws, out0, traj);
    hipLaunchKernelGGL(gather_logqp, dim3(64), dim3(256), 0, stream, traj, out1);
}

// Round 5
// 323.348 us; speedup vs baseline: 3.0497x; 3.0497x over previous
//
#include <hip/hip_runtime.h>
#include <math.h>
#include <stdint.h>

#define NPART 16384
#define NSTEP 40
#define DIMA  22

typedef __attribute__((ext_vector_type(8))) short short8;
typedef __attribute__((ext_vector_type(4))) float floatx4;
typedef __attribute__((ext_vector_type(4))) int   intx4;

// LDS weight-image byte offsets — TRUE 1024-B tiles (64 lanes x 16 B).
// kt=2 (k in [64,96)) stored as 512-B HALF-tiles (lanes 0..31 = quads 0,1,
// i.e. k in [64,80)); consumer zeroes quads 2,3 registers (k>=80 is pad).
#define AIN_B    0        // 5 mt x 1024          (k>=24 zeroed in image)
#define AH_B     5120     // 20 groups(layer,mt) x (1024+1024+512)
#define AOUT_B   56320    // 2 mt x (1024+1024+512)  (m>=20 zeroed)
#define BIN_B    61440    // 80 f32
#define BH_B     61760    // 320 f32
#define BOUT_B   63040    // 32 f32
#define IMG_BYTES  63168
#define IMG_DWORDS 15792
// workspace dword offsets
#define U_OFF     15792
#define TRAJ_OFF  15952
#define OUT0_ELEMS 13434880

union V4 { intx4 i; short8 s; floatx4 f; };

__device__ __forceinline__ uint32_t bf16r(float x) {
    uint32_t u = __float_as_uint(x);
    u += 0x7FFFu + ((u >> 16) & 1u);   // RNE
    return u >> 16;
}
__device__ __forceinline__ uint32_t pk2(float a0, float a1) {
    return bf16r(a0) | (bf16r(a1) << 16);
}
__device__ __forceinline__ float fast_tanh(float x) {
    float e = __expf(2.0f * x);
    return 1.0f - 2.0f * __builtin_amdgcn_rcpf(e + 1.0f);
}

// ---- pre-pass 1: bf16 A-fragment image (proper tiles) + f32 biases ----
// Full tile: 256 dwords; lane = (dw>>2)&63, w = dw&3.
// Lane (quad,m): A[m][k = quad*8 + 2w + {0,1}]  (m120-verified layout).
__global__ void prep_weights(const float* __restrict__ dw_in,
                             const float* __restrict__ dw_h,
                             const float* __restrict__ dw_out,
                             const float* __restrict__ db_in,
                             const float* __restrict__ db_h,
                             const float* __restrict__ db_out,
                             uint32_t* __restrict__ img) {
    int di = blockIdx.x * 256 + threadIdx.x;
    if (di >= IMG_DWORDS) return;
    if (di < 1280) {                          // AIN: 5 full tiles, K=32 (k>=24 zero)
        int mt = di >> 8, r = di & 255, lane = r >> 2, w = r & 3;
        int m = mt * 16 + (lane & 15), k = (lane >> 4) * 8 + 2 * w;
        float v0 = (k < 24)     ? dw_in[m * 24 + k]     : 0.f;
        float v1 = (k + 1 < 24) ? dw_in[m * 24 + k + 1] : 0.f;
        img[di] = pk2(v0, v1);
    } else if (di < 14080) {                  // AH: 20 groups x 640 dwords
        int q = di - 1280, g = q / 640, r = q % 640;
        int layer = g / 5, mt = g % 5;
        int lane, w, k;
        if (r < 512) { int kt = r >> 8, rr = r & 255; lane = rr >> 2; w = rr & 3;
                       k = kt * 32 + (lane >> 4) * 8 + 2 * w; }
        else         { int rr = r - 512; lane = rr >> 2; w = rr & 3;
                       k = 64 + (lane >> 4) * 8 + 2 * w; }
        int m = mt * 16 + (lane & 15);
        img[di] = pk2(dw_h[layer * 6400 + m * 80 + k],
                      dw_h[layer * 6400 + m * 80 + k + 1]);
    } else if (di < 15360) {                  // AOUT: 2 groups x 640 dwords
        int q = di - 14080, mt = q / 640, r = q % 640;
        int lane, w, k;
        if (r < 512) { int kt = r >> 8, rr = r & 255; lane = rr >> 2; w = rr & 3;
                       k = kt * 32 + (lane >> 4) * 8 + 2 * w; }
        else         { int rr = r - 512; lane = rr >> 2; w = rr & 3;
                       k = 64 + (lane >> 4) * 8 + 2 * w; }
        int m = mt * 16 + (lane & 15);
        float v0 = 0.f, v1 = 0.f;
        if (m < 20) { v0 = dw_out[m * 80 + k]; v1 = dw_out[m * 80 + k + 1]; }
        img[di] = pk2(v0, v1);
    } else if (di < 15440) {
        ((float*)img)[di] = db_in[di - 15360];
    } else if (di < 15760) {
        ((float*)img)[di] = db_h[di - 15440];
    } else {
        int j = di - 15760;
        ((float*)img)[di] = (j < 20) ? db_out[j] : 0.f;
    }
}

// ---- pre-pass 2: t-MLP u(t_i), fp32 ----
__global__ void prep_u(const float* __restrict__ t_arr,
                       const float* __restrict__ tw_in, const float* __restrict__ tb_in,
                       const float* __restrict__ tw_h,  const float* __restrict__ tb_h,
                       const float* __restrict__ tw_out,const float* __restrict__ tb_out,
                       float* __restrict__ uws) {
    int i = threadIdx.x;
    if (i >= NSTEP) return;
    float ti = t_arr[i];
    float h[20], h2[20];
    #pragma unroll
    for (int j = 0; j < 20; j++) {
        float v = tw_in[j] * ti + tb_in[j];
        h[j] = v > 0.f ? v : 0.f;
    }
    #pragma unroll
    for (int l = 0; l < 4; l++) {
        #pragma unroll
        for (int j = 0; j < 20; j++) {
            float a = tb_h[l * 20 + j];
            #pragma unroll
            for (int k = 0; k < 20; k++) a += tw_h[(l * 20 + j) * 20 + k] * h[k];
            h2[j] = a > 0.f ? a : 0.f;
        }
        #pragma unroll
        for (int j = 0; j < 20; j++) h[j] = h2[j];
    }
    #pragma unroll
    for (int c = 0; c < 4; c++) {
        float a = tb_out[c];
        #pragma unroll
        for (int k = 0; k < 20; k++) a += tw_out[c * 20 + k] * h[k];
        uws[i * 4 + c] = a;
    }
}

// D-layout -> B-frag: dest slot (quad, word w) must hold feature
// e = kt*32 + quad*8 + 2w+{0,1}; source = PK[e>>4][(e>>1)&1] at lane
// ((e>>2)&3)*16+n15 = (((w>>1)+2*quad)&3)*16+n15.  Tile 2: e>=80 -> 0.
#define BUILD_B3(B0, B1, B2, PK)                                               \
    {                                                                          \
        _Pragma("unroll")                                                      \
        for (int w = 0; w < 4; w++) {                                          \
            int s = (((w >> 1) + 2 * quad) & 3) * 16 + n15;                    \
            int a0 = __shfl((int)PK[0][w & 1], s);                             \
            int a1 = __shfl((int)PK[1][w & 1], s);                             \
            B0[w] = (quad >= 2) ? a1 : a0;                                     \
            int a2 = __shfl((int)PK[2][w & 1], s);                             \
            int a3 = __shfl((int)PK[3][w & 1], s);                             \
            B1[w] = (quad >= 2) ? a3 : a2;                                     \
            int a4 = __shfl((int)PK[4][w & 1], s);                             \
            B2[w] = (quad >= 2) ? 0 : a4;                                     \
        }                                                                      \
    }

__global__ __launch_bounds__(256) void sde_mfma(
    const float* __restrict__ z,     const float* __restrict__ t_arr,
    const float* __restrict__ Tx,    const float* __restrict__ noise,
    const float* __restrict__ ws_f,
    float* __restrict__ out0,        float* __restrict__ traj) {
    __shared__ __align__(16) uint8_t lds[IMG_BYTES];
    const int tid = threadIdx.x;
    {
        const uint32_t* src = (const uint32_t*)ws_f;
        uint32_t* dst = (uint32_t*)lds;
        for (int idx = tid; idx < IMG_DWORDS; idx += 256) dst[idx] = src[idx];
    }
    __syncthreads();

    const int lane = tid & 63;
    const int n15  = lane & 15;
    const int quad = lane >> 4;
    const int wv   = tid >> 6;
    const int n    = blockIdx.x * 64 + wv * 16 + n15;
    const float Txb = Tx[blockIdx.x];
    const float dtv = t_arr[1] - t_arr[0];
    const float sdt = sqrtf(dtv);
    const float* uws = ws_f + U_OFF;
    const intx4 zero4 = {0, 0, 0, 0};

    // state in D-layout: y0[r] = y[quad*4+r]; y1[r] = y[16+quad*4+r] (quad0)
    float y0[4], y1[4] = {0.f, 0.f, 0.f, 0.f};
    {
        floatx4 zv = *(const floatx4*)(z + (size_t)n * 20 + quad * 4);
        #pragma unroll
        for (int r = 0; r < 4; r++) y0[r] = zv[r];
        *(floatx4*)(out0 + (size_t)n * 20 + quad * 4) = zv;
        if (quad == 0) {
            floatx4 z2 = *(const floatx4*)(z + (size_t)n * 20 + 16);
            #pragma unroll
            for (int r = 0; r < 4; r++) y1[r] = z2[r];
            *(floatx4*)(out0 + (size_t)n * 20 + 16) = z2;
            traj[n] = 0.f;
        }
    }

    double lq = 0.0;
    for (int i = 0; i < NSTEP; i++) {
        float ut0 = uws[i * 4 + 0] * Txb, ut1 = uws[i * 4 + 1] * Txb;
        float ut2 = uws[i * 4 + 2] * Txb, ut3 = uws[i * 4 + 3] * Txb;

        // ---- input B-frag: x = [y(20), u_t(4), 0 x 8] ----
        uint32_t p0[2] = { pk2(y0[0], y0[1]), pk2(y0[2], y0[3]) };
        uint32_t p1[2] = { 0, 0 };
        if (quad == 0)      { p1[0] = pk2(y1[0], y1[1]); p1[1] = pk2(y1[2], y1[3]); }
        else if (quad == 1) { p1[0] = pk2(ut0, ut1);     p1[1] = pk2(ut2, ut3); }
        V4 bin;
        #pragma unroll
        for (int w = 0; w < 4; w++) {
            int s = (((w >> 1) + 2 * quad) & 3) * 16 + n15;
            int lo = __shfl((int)p0[w & 1], s);
            int hi = __shfl((int)p1[w & 1], s);
            bin.i[w] = (quad >= 2) ? hi : lo;
        }

        // ---- input layer: relu(W_in x + b) ----
        floatx4 acc[5];
        #pragma unroll
        for (int mt = 0; mt < 5; mt++) {
            V4 a; a.i = *(const intx4*)(lds + AIN_B + mt * 1024 + lane * 16);
            floatx4 c = *(const floatx4*)(lds + BIN_B + (mt * 16 + quad * 4) * 4);
            acc[mt] = __builtin_amdgcn_mfma_f32_16x16x32_bf16(a.s, bin.s, c, 0, 0, 0);
        }
        uint32_t pkA[5][2];
        #pragma unroll
        for (int mt = 0; mt < 5; mt++) {
            pkA[mt][0] = pk2(fmaxf(acc[mt][0], 0.f), fmaxf(acc[mt][1], 0.f));
            pkA[mt][1] = pk2(fmaxf(acc[mt][2], 0.f), fmaxf(acc[mt][3], 0.f));
        }

        // ---- 4 hidden tanh layers ----
        #pragma unroll
        for (int l = 0; l < 4; l++) {
            int B0[4], B1[4], B2[4];
            BUILD_B3(B0, B1, B2, pkA);
            V4 b0, b1, b2;
            b0.i = (intx4){B0[0], B0[1], B0[2], B0[3]};
            b1.i = (intx4){B1[0], B1[1], B1[2], B1[3]};
            b2.i = (intx4){B2[0], B2[1], B2[2], B2[3]};
            #pragma unroll
            for (int mt = 0; mt < 5; mt++) {
                const uint8_t* grp = lds + AH_B + (size_t)(l * 5 + mt) * 2560;
                floatx4 c = *(const floatx4*)(lds + BH_B + l * 320 + (mt * 16 + quad * 4) * 4);
                V4 a0; a0.i = *(const intx4*)(grp + lane * 16);
                V4 a1; a1.i = *(const intx4*)(grp + 1024 + lane * 16);
                V4 a2; a2.i = *(const intx4*)(grp + 2048 + (lane & 31) * 16);
                if (quad >= 2) a2.i = zero4;      // k in [80,96) is pad
                c = __builtin_amdgcn_mfma_f32_16x16x32_bf16(a0.s, b0.s, c, 0, 0, 0);
                c = __builtin_amdgcn_mfma_f32_16x16x32_bf16(a1.s, b1.s, c, 0, 0, 0);
                c = __builtin_amdgcn_mfma_f32_16x16x32_bf16(a2.s, b2.s, c, 0, 0, 0);
                acc[mt] = c;
            }
            #pragma unroll
            for (int mt = 0; mt < 5; mt++) {
                pkA[mt][0] = pk2(fast_tanh(acc[mt][0]), fast_tanh(acc[mt][1]));
                pkA[mt][1] = pk2(fast_tanh(acc[mt][2]), fast_tanh(acc[mt][3]));
            }
        }

        // ---- output layer (M=20 padded to 32) ----
        int B0[4], B1[4], B2[4];
        BUILD_B3(B0, B1, B2, pkA);
        V4 b0, b1, b2;
        b0.i = (intx4){B0[0], B0[1], B0[2], B0[3]};
        b1.i = (intx4){B1[0], B1[1], B1[2], B1[3]};
        b2.i = (intx4){B2[0], B2[1], B2[2], B2[3]};
        floatx4 oacc[2];
        #pragma unroll
        for (int mt = 0; mt < 2; mt++) {
            const uint8_t* grp = lds + AOUT_B + (size_t)mt * 2560;
            floatx4 c = *(const floatx4*)(lds + BOUT_B + (mt * 16 + quad * 4) * 4);
            V4 a0; a0.i = *(const intx4*)(grp + lane * 16);
            V4 a1; a1.i = *(const intx4*)(grp + 1024 + lane * 16);
            V4 a2; a2.i = *(const intx4*)(grp + 2048 + (lane & 31) * 16);
            if (quad >= 2) a2.i = zero4;
            c = __builtin_amdgcn_mfma_f32_16x16x32_bf16(a0.s, b0.s, c, 0, 0, 0);
            c = __builtin_amdgcn_mfma_f32_16x16x32_bf16(a1.s, b1.s, c, 0, 0, 0);
            c = __builtin_amdgcn_mfma_f32_16x16x32_bf16(a2.s, b2.s, c, 0, 0, 0);
            oacc[mt] = c;
        }

        // ---- SDE update + logqp ----
        float part = 0.f;
        size_t nbase = ((size_t)i * NPART + n) * DIMA;
        size_t obase = ((size_t)(i + 1) * NPART + n) * 20;
        floatx4 st;
        #pragma unroll
        for (int r = 0; r < 4; r++) {
            float o = oacc[0][r];
            float y = y0[r];
            float f = o + y;                 // f = mlp - h, h = -y
            float uu = 2.f * o + 4.f * y;    // (f - h)/sigma
            part += uu * uu;
            float dW = noise[nbase + quad * 4 + r];
            y0[r] = y + f * dtv + (0.5f * sdt) * dW;
            st[r] = y0[r];
        }
        *(floatx4*)(out0 + obase + quad * 4) = st;
        if (quad == 0) {
            floatx4 st2;
            #pragma unroll
            for (int r = 0; r < 4; r++) {
                float o = oacc[1][r];
                float y = y1[r];
                float f = o + y;
                float uu = 2.f * o + 4.f * y;
                part += uu * uu;
                float dW = noise[nbase + 16 + r];
                y1[r] = y + f * dtv + (0.5f * sdt) * dW;
                st2[r] = y1[r];
            }
            *(floatx4*)(out0 + obase + 16) = st2;
        }
        part += __shfl_xor(part, 16);
        part += __shfl_xor(part, 32);
        lq += 0.5 * (double)part * (double)dtv;
        if (quad == 0) traj[(size_t)(i + 1) * NPART + n] = (float)lq;
    }
}

__global__ void gather_logqp(const float* __restrict__ traj, float* __restrict__ out1) {
    int i = blockIdx.x * 256 + threadIdx.x;
    if (i < NPART) out1[i] = traj[(size_t)41 * i + 40];
}

extern "C" void kernel_launch(void* const* d_in, const int* in_sizes, int n_in,
                              void* d_out, int out_size, void* d_ws, size_t ws_size,
                              hipStream_t stream) {
    const float* z      = (const float*)d_in[0];
    const float* t_arr  = (const float*)d_in[1];
    const float* Tx     = (const float*)d_in[2];
    const float* noise  = (const float*)d_in[3];
    const float* tw_in  = (const float*)d_in[4];
    const float* tb_in  = (const float*)d_in[5];
    const float* tw_h   = (const float*)d_in[6];
    const float* tb_h   = (const float*)d_in[7];
    const float* tw_out = (const float*)d_in[8];
    const float* tb_out = (const float*)d_in[9];
    const float* dw_in  = (const float*)d_in[10];
    const float* db_in  = (const float*)d_in[11];
    const float* dw_h   = (const float*)d_in[12];
    const float* db_h   = (const float*)d_in[13];
    const float* dw_out = (const float*)d_in[14];
    const float* db_out = (const float*)d_in[15];

    uint32_t* img  = (uint32_t*)d_ws;
    float*    wsf  = (float*)d_ws;
    float*    uws  = wsf + U_OFF;
    float*    traj = wsf + TRAJ_OFF;
    float*    out0 = (float*)d_out;
    float*    out1 = out0 + OUT0_ELEMS;

    hipLaunchKernelGGL(prep_weights, dim3(62), dim3(256), 0, stream,
                       dw_in, dw_h, dw_out, db_in, db_h, db_out, img);
    hipLaunchKernelGGL(prep_u, dim3(1), dim3(64), 0, stream,
                       t_arr, tw_in, tb_in, tw_h, tb_h, tw_out, tb_out, uws);
    hipLaunchKernelGGL(sde_mfma, dim3(256), dim3(256), 0, stream,
                       z, t_arr, Tx, noise, wsf, out0, traj);
    hipLaunchKernelGGL(gather_logqp, dim3(64), dim3(256), 0, stream, traj, out1);
}